// Round 7
// baseline (253.405 us; speedup 1.0000x reference)
//
#include <hip/hip_runtime.h>

// Problem constants (B=2, S=2048, H=8, E=64).
// Harness passes f16 tensors upcast to FLOAT32 (in and out). Internally f16
// compute (lossless re-narrowing of f16-origin data), fp32 MFMA accumulation.
#define S_LEN 2048
#define NH    8
#define EMB   64
#define BM    64    // q rows per block (16 per wave)
#define BN    128   // kv tile length
#define NSPLIT 2    // KV splits: 16 bh x 32 qt x 2 = 1024 blocks
#define PSTR  136   // padded LDS row stride for P (f16 elems)
#define M_INIT  (-1.0e4f)
#define EXP_CLAMP (-80.0f)

typedef _Float16 half8   __attribute__((ext_vector_type(8)));
typedef float    float4_t __attribute__((ext_vector_type(4)));
typedef float    float8_t __attribute__((ext_vector_type(8)));

__device__ inline half8 cvt8(const float* p) {
    float8_t f = *reinterpret_cast<const float8_t*>(p);
    half8 h;
    #pragma unroll
    for (int j = 0; j < 8; ++j) h[j] = (_Float16)f[j];
    return h;
}

// ---------------------------------------------------------------------------
// Projection (proven): Out[b,h,s,f] = f16(sum_e X*W + b) * scale, [B,H,S,E].
// ---------------------------------------------------------------------------
template<bool F16OUT>
__global__ __launch_bounds__(256) void proj_one(
    const float* __restrict__ X, const float* __restrict__ W,
    const float* __restrict__ bias, void* __restrict__ OutP, float scale)
{
    const int tid  = threadIdx.x;
    const int lane = tid & 63;
    const int wave = tid >> 6;
    const int l15  = lane & 15;
    const int quad = lane >> 4;
    const int gwave = blockIdx.x * 4 + wave;

    half8 wf[4][2];
    #pragma unroll
    for (int ft = 0; ft < 4; ++ft)
        #pragma unroll
        for (int ks = 0; ks < 2; ++ks)
            wf[ft][ks] = cvt8(W + (ft * 16 + l15) * 64 + ks * 32 + quad * 8);
    float bv[4];
    #pragma unroll
    for (int ft = 0; ft < 4; ++ft) bv[ft] = bias[ft * 16 + l15];

    #pragma unroll
    for (int rt2 = 0; rt2 < 2; ++rt2) {
        const int rt = gwave * 2 + rt2;
        const int arow = rt * 16 + l15;
        half8 xf[2];
        #pragma unroll
        for (int ks = 0; ks < 2; ++ks)
            xf[ks] = cvt8(X + (long)arow * 64 + ks * 32 + quad * 8);
        float4_t acc[4];
        #pragma unroll
        for (int ft = 0; ft < 4; ++ft) {
            acc[ft] = (float4_t){0.f, 0.f, 0.f, 0.f};
            #pragma unroll
            for (int ks = 0; ks < 2; ++ks)
                acc[ft] = __builtin_amdgcn_mfma_f32_16x16x32_f16(
                    xf[ks], wf[ft][ks], acc[ft], 0, 0, 0);
        }
        #pragma unroll
        for (int r = 0; r < 4; ++r) {
            const int row = rt * 16 + quad * 4 + r;     // (b*S+s)*H+h
            const int b = row >> 14;
            const int s = (row >> 3) & 2047;
            const int h = row & 7;
            const long orow = ((long)(b * NH + h) * S_LEN + s) * EMB;
            #pragma unroll
            for (int ft = 0; ft < 4; ++ft) {
                const _Float16 v =
                    (_Float16)(acc[ft][r] + bv[ft]) * (_Float16)scale;
                if (F16OUT) ((_Float16*)OutP)[orow + ft * 16 + l15] = v;
                else        ((float*)OutP)[orow + ft * 16 + l15] = (float)v;
            }
        }
    }
}

// ---------------------------------------------------------------------------
// V transpose: [bh][t][e] -> [bh][e][t] via 64x64 LDS tiles (pad 66: write
// banks 8i+j -> 2-way max; read banks e+8tq -> 2-way max; both free).
// ---------------------------------------------------------------------------
__global__ __launch_bounds__(256) void vtrans(
    const _Float16* __restrict__ Vin, _Float16* __restrict__ VTout)
{
    __shared__ _Float16 L[64 * 66];
    const int tid = threadIdx.x;
    const int bh  = blockIdx.x >> 5;
    const int t0  = (blockIdx.x & 31) * 64;
    const _Float16* src = Vin + ((long)bh * S_LEN + t0) * EMB;
    #pragma unroll
    for (int p = 0; p < 2; ++p) {
        const int chunk = p * 256 + tid;
        const int tl = chunk >> 3, e0 = (chunk & 7) * 8;
        half8 v = *reinterpret_cast<const half8*>(src + tl * EMB + e0);
        #pragma unroll
        for (int j = 0; j < 8; ++j) L[(e0 + j) * 66 + tl] = v[j];
    }
    __syncthreads();
    const int e = tid >> 2, tq = (tid & 3) * 16;
    _Float16* dst = VTout + ((long)bh * EMB + e) * S_LEN + t0 + tq;
    half8 a, b;
    #pragma unroll
    for (int k = 0; k < 8; ++k) a[k] = L[e * 66 + tq + k];
    #pragma unroll
    for (int k = 0; k < 8; ++k) b[k] = L[e * 66 + tq + 8 + k];
    *reinterpret_cast<half8*>(dst)     = a;   // 16B-aligned (tq*2 = 32B mult)
    *reinterpret_cast<half8*>(dst + 8) = b;
}

// ---------------------------------------------------------------------------
// Pass 1: flash attention partials, KV-split=2. BARRIER-FREE: K and V^T
// fragments are contiguous 16B global loads (L2-resident); LDS holds only the
// per-wave P buffer (C-layout -> A-layout round trip, same-wave lgkmcnt).
// ---------------------------------------------------------------------------
__global__ __launch_bounds__(256) void attn_part(
    const _Float16* __restrict__ K, const _Float16* __restrict__ VT,
    const float* __restrict__ Qbuf, _Float16* __restrict__ part,
    float* __restrict__ stats)
{
    __shared__ __align__(16) _Float16 Pl[4][16 * PSTR];  // per-wave P: [m][t]

    const int tid  = threadIdx.x;
    const int lane = tid & 63;
    const int wave = tid >> 6;
    const int l15  = lane & 15;
    const int quad = lane >> 4;
    const int bx   = blockIdx.x;          // bh*64 + qt*2 + sp
    const int bh   = bx >> 6;
    const int qt   = (bx >> 1) & 31;
    const int sp   = bx & 1;
    const long base = (long)bh * S_LEN * EMB;
    const int qrow0 = qt * BM + wave * 16;
    // V^T row base for this lane: e = et*16 + l15, t chunk = t0 + ts*32 + quad*8
    const _Float16* vbase = VT + ((long)bh * EMB + l15) * S_LEN + quad * 8;

    half8 qf[2];
    #pragma unroll
    for (int ks = 0; ks < 2; ++ks)
        qf[ks] = cvt8(Qbuf + base + (long)(qrow0 + l15) * EMB + ks * 32 + quad * 8);

    float4_t o[4];
    #pragma unroll
    for (int et = 0; et < 4; ++et) o[et] = (float4_t){0.f, 0.f, 0.f, 0.f};
    float m_run[4], l_run[4];
    #pragma unroll
    for (int r = 0; r < 4; ++r) { m_run[r] = M_INIT; l_run[r] = 0.f; }

    const int kt0 = sp * (S_LEN / BN / NSPLIT);          // 8 tiles per split
    for (int kti = 0; kti < S_LEN / BN / NSPLIT; ++kti) {
        const int t0 = (kt0 + kti) * BN;

        // S = Q K^T : 8 n-tiles of 16 cols, fp32 accumulate (K from global)
        float4_t sacc[8];
        #pragma unroll
        for (int nt = 0; nt < 8; ++nt) sacc[nt] = (float4_t){0.f, 0.f, 0.f, 0.f};
        #pragma unroll
        for (int nt = 0; nt < 8; ++nt) {
            const long nrow = base + (long)(t0 + nt * 16 + l15) * EMB;
            #pragma unroll
            for (int ks = 0; ks < 2; ++ks) {
                half8 kf = *reinterpret_cast<const half8*>(
                    K + nrow + ks * 32 + quad * 8);
                sacc[nt] = __builtin_amdgcn_mfma_f32_16x16x32_f16(
                    qf[ks], kf, sacc[nt], 0, 0, 0);
            }
        }

        // online softmax; lane holds rows quad*4+r, cols l15 (+16*nt)
        float mx[4];
        #pragma unroll
        for (int r = 0; r < 4; ++r) {
            mx[r] = sacc[0][r];
            #pragma unroll
            for (int nt = 1; nt < 8; ++nt) mx[r] = fmaxf(mx[r], sacc[nt][r]);
        }
        #pragma unroll
        for (int off = 1; off < 16; off <<= 1)
            #pragma unroll
            for (int r = 0; r < 4; ++r)
                mx[r] = fmaxf(mx[r], __shfl_xor(mx[r], off));

        float alpha[4], rsum[4];
        #pragma unroll
        for (int r = 0; r < 4; ++r) {
            const float mn = fmaxf(m_run[r], mx[r]);
            alpha[r] = __expf(fmaxf(m_run[r] - mn, EXP_CLAMP));
            m_run[r] = mn;
            rsum[r] = 0.f;
        }
        _Float16* Pw = Pl[wave];
        #pragma unroll
        for (int nt = 0; nt < 8; ++nt)
            #pragma unroll
            for (int r = 0; r < 4; ++r) {
                const float p = __expf(fmaxf(sacc[nt][r] - m_run[r], EXP_CLAMP));
                rsum[r] += p;
                Pw[(quad * 4 + r) * PSTR + nt * 16 + l15] = (_Float16)p;
            }
        #pragma unroll
        for (int off = 1; off < 16; off <<= 1)
            #pragma unroll
            for (int r = 0; r < 4; ++r)
                rsum[r] += __shfl_xor(rsum[r], off);
        #pragma unroll
        for (int r = 0; r < 4; ++r)
            l_run[r] = l_run[r] * alpha[r] + rsum[r];
        #pragma unroll
        for (int et = 0; et < 4; ++et)
            #pragma unroll
            for (int r = 0; r < 4; ++r)
                o[et][r] *= alpha[r];
        // no barrier: P write->read is same-wave (compiler lgkmcnt)

        // O += P V : A-frag = P[m=l15][t=ts*32+quad*8+j], B-frag = V^T global
        #pragma unroll
        for (int ts = 0; ts < 4; ++ts) {
            half8 pf = *reinterpret_cast<const half8*>(
                &Pw[l15 * PSTR + ts * 32 + quad * 8]);
            #pragma unroll
            for (int et = 0; et < 4; ++et) {
                half8 vf = *reinterpret_cast<const half8*>(
                    vbase + (long)(et * 16) * S_LEN + t0 + ts * 32);
                o[et] = __builtin_amdgcn_mfma_f32_16x16x32_f16(pf, vf, o[et], 0, 0, 0);
            }
        }
    }

    // epilogue: normalized partial O-hat (f16) + (m,l) stats.
    #pragma unroll
    for (int r = 0; r < 4; ++r) {
        const float inv = 1.f / l_run[r];
        const int row = qrow0 + quad * 4 + r;            // 0..2047 within head
        const int R = bh * S_LEN + row;                  // 0..32767 global row
        const long prow = ((long)sp * 32768 + R) * EMB;
        #pragma unroll
        for (int et = 0; et < 4; ++et)
            part[prow + et * 16 + l15] = (_Float16)(o[et][r] * inv);
        if (l15 == 0) {
            stats[sp * 32768 + R] = m_run[r];
            stats[2 * 32768 + sp * 32768 + R] = l_run[r];
        }
    }
}

// ---------------------------------------------------------------------------
// Pass 2: combine the 2 partials. O = w0*Ohat0 + w1*Ohat1, f16-round, f32 store.
// ---------------------------------------------------------------------------
__global__ __launch_bounds__(256) void attn_combine(
    const _Float16* __restrict__ part, const float* __restrict__ stats,
    float* __restrict__ out)
{
    const int gid = blockIdx.x * 256 + threadIdx.x;      // 131072 threads
    const int R  = gid >> 2;
    const int c0 = (gid & 3) * 16;
    const float m0 = stats[R],           m1 = stats[32768 + R];
    const float l0 = stats[2*32768 + R], l1 = stats[3*32768 + R];
    const float M  = fmaxf(m0, m1);
    float w0 = l0 * __expf(fmaxf(m0 - M, EXP_CLAMP));
    float w1 = l1 * __expf(fmaxf(m1 - M, EXP_CLAMP));
    const float rinv = 1.f / (w0 + w1);
    w0 *= rinv; w1 *= rinv;
    const long i0 = (long)R * EMB + c0;
    const long i1 = i0 + (long)32768 * EMB;
    #pragma unroll
    for (int h = 0; h < 2; ++h) {
        half8 a = *reinterpret_cast<const half8*>(part + i0 + h * 8);
        half8 b = *reinterpret_cast<const half8*>(part + i1 + h * 8);
        #pragma unroll
        for (int j = 0; j < 8; ++j)
            out[i0 + h * 8 + j] =
                (float)(_Float16)(w0 * (float)a[j] + w1 * (float)b[j]);
    }
}

// ---------------------------------------------------------------------------
// Buffer plan (no d_ws; all guaranteed-size, stream-ordered):
//   proj Q: d_in[0](f32) -> d_out (f32, f16-rounded, pre-scaled 0.125)
//   proj K: d_in[1](f32) -> d_in[0][0..4MB) as f16 [bh][t][e]
//   proj V: d_in[2](f32) -> d_in[1][0..4MB) as f16 [bh][t][e]
//   vtrans: d_in[1][0..4MB) -> d_in[1][4..8MB) as f16 [bh][e][t]
//   pass1:  K=d_in[0], VT=d_in[1]+4MB, Q=d_out (read-only);
//           partials -> d_in[2] (8MB), stats -> d_in[0]+4MB (512KB)
//   pass2:  combine -> d_out
// ---------------------------------------------------------------------------
extern "C" void kernel_launch(void* const* d_in, const int* in_sizes, int n_in,
                              void* d_out, int out_size, void* d_ws, size_t ws_size,
                              hipStream_t stream) {
    const float* q_in = (const float*)d_in[0];
    const float* k_in = (const float*)d_in[1];
    const float* v_in = (const float*)d_in[2];
    const float* Wq   = (const float*)d_in[3];
    const float* bq   = (const float*)d_in[4];
    const float* Wk   = (const float*)d_in[5];
    const float* bk   = (const float*)d_in[6];
    const float* Wv   = (const float*)d_in[7];
    const float* bv   = (const float*)d_in[8];
    float* out = (float*)d_out;

    _Float16* Kf16  = (_Float16*)d_in[0];
    _Float16* Vf16  = (_Float16*)d_in[1];
    _Float16* VTf16 = Vf16 + (long)2 * 1024 * 1024;      // +4 MB
    _Float16* partb = (_Float16*)d_in[2];
    float*    stats = (float*)((char*)d_in[0] + (4u << 20));

    proj_one<false><<<256, 256, 0, stream>>>(q_in, Wq, bq, out, 0.125f);
    proj_one<true><<<256, 256, 0, stream>>>(k_in, Wk, bk, (void*)Kf16, 1.0f);
    proj_one<true><<<256, 256, 0, stream>>>(v_in, Wv, bv, (void*)Vf16, 1.0f);
    vtrans<<<512, 256, 0, stream>>>(Vf16, VTf16);
    attn_part<<<1024, 256, 0, stream>>>(Kf16, VTf16, out, partb, stats);
    attn_combine<<<512, 256, 0, stream>>>(partb, stats, out);
}

// Round 8
// 202.622 us; speedup vs baseline: 1.2506x; 1.2506x over previous
//
#include <hip/hip_runtime.h>

// Problem constants (B=2, S=2048, H=8, E=64).
// Harness passes f16 tensors upcast to FLOAT32 (in and out). Internally f16
// compute (lossless re-narrowing of f16-origin data), fp32 MFMA accumulation.
#define S_LEN 2048
#define NH    8
#define EMB   64
#define BM    64    // q rows per block (16 per wave)
#define BN    128   // kv tile length
#define NSPLIT 2    // KV splits: 16 bh x 32 qt x 2 = 1024 blocks
#define PSTR  136   // padded LDS row stride for P (f16 elems)
#define M_INIT  (-1.0e4f)
#define EXP_CLAMP (-80.0f)

typedef _Float16 half8   __attribute__((ext_vector_type(8)));
typedef float    float4_t __attribute__((ext_vector_type(4)));
typedef float    float8_t __attribute__((ext_vector_type(8)));

__device__ inline half8 cvt8(const float* p) {
    float8_t f = *reinterpret_cast<const float8_t*>(p);
    half8 h;
    #pragma unroll
    for (int j = 0; j < 8; ++j) h[j] = (_Float16)f[j];
    return h;
}

// ---------------------------------------------------------------------------
// Projection (proven): Out[b,h,s,f] = f16(sum_e X*W + b) * scale, [B,H,S,E].
// ---------------------------------------------------------------------------
template<bool F16OUT>
__global__ __launch_bounds__(256) void proj_one(
    const float* __restrict__ X, const float* __restrict__ W,
    const float* __restrict__ bias, void* __restrict__ OutP, float scale)
{
    const int tid  = threadIdx.x;
    const int lane = tid & 63;
    const int wave = tid >> 6;
    const int l15  = lane & 15;
    const int quad = lane >> 4;
    const int gwave = blockIdx.x * 4 + wave;

    half8 wf[4][2];
    #pragma unroll
    for (int ft = 0; ft < 4; ++ft)
        #pragma unroll
        for (int ks = 0; ks < 2; ++ks)
            wf[ft][ks] = cvt8(W + (ft * 16 + l15) * 64 + ks * 32 + quad * 8);
    float bv[4];
    #pragma unroll
    for (int ft = 0; ft < 4; ++ft) bv[ft] = bias[ft * 16 + l15];

    #pragma unroll
    for (int rt2 = 0; rt2 < 2; ++rt2) {
        const int rt = gwave * 2 + rt2;
        const int arow = rt * 16 + l15;
        half8 xf[2];
        #pragma unroll
        for (int ks = 0; ks < 2; ++ks)
            xf[ks] = cvt8(X + (long)arow * 64 + ks * 32 + quad * 8);
        float4_t acc[4];
        #pragma unroll
        for (int ft = 0; ft < 4; ++ft) {
            acc[ft] = (float4_t){0.f, 0.f, 0.f, 0.f};
            #pragma unroll
            for (int ks = 0; ks < 2; ++ks)
                acc[ft] = __builtin_amdgcn_mfma_f32_16x16x32_f16(
                    xf[ks], wf[ft][ks], acc[ft], 0, 0, 0);
        }
        #pragma unroll
        for (int r = 0; r < 4; ++r) {
            const int row = rt * 16 + quad * 4 + r;     // (b*S+s)*H+h
            const int b = row >> 14;
            const int s = (row >> 3) & 2047;
            const int h = row & 7;
            const long orow = ((long)(b * NH + h) * S_LEN + s) * EMB;
            #pragma unroll
            for (int ft = 0; ft < 4; ++ft) {
                const _Float16 v =
                    (_Float16)(acc[ft][r] + bv[ft]) * (_Float16)scale;
                if (F16OUT) ((_Float16*)OutP)[orow + ft * 16 + l15] = v;
                else        ((float*)OutP)[orow + ft * 16 + l15] = (float)v;
            }
        }
    }
}

// ---------------------------------------------------------------------------
// V transpose into interleaved layout VT8[bh][t/8][e][t%8]:
// element (bh,e,t) at ((bh*256 + t/8)*64 + e)*8 + (t&7).
// A PV B-fragment (fixed e, 8 consecutive t) is one 16B load, and the 16
// l15-lanes are CONTIGUOUS (16B apart) -> coalesced, channel-spread (the
// plain [e][t] layout's 4096B row stride put all 16 lanes on one L2 channel).
// ---------------------------------------------------------------------------
__global__ __launch_bounds__(256) void vtrans(
    const _Float16* __restrict__ Vin, _Float16* __restrict__ VT8)
{
    __shared__ _Float16 L[64 * 66];
    const int tid = threadIdx.x;
    const int bh  = blockIdx.x >> 5;
    const int t0  = (blockIdx.x & 31) * 64;
    const _Float16* src = Vin + ((long)bh * S_LEN + t0) * EMB;
    #pragma unroll
    for (int p = 0; p < 2; ++p) {
        const int chunk = p * 256 + tid;
        const int tl = chunk >> 3, e0 = (chunk & 7) * 8;
        half8 v = *reinterpret_cast<const half8*>(src + tl * EMB + e0);
        #pragma unroll
        for (int j = 0; j < 8; ++j) L[(e0 + j) * 66 + tl] = v[j];
    }
    __syncthreads();
    // 8 t-chunks x 64 e = 512 units of 8 elems; 2 units/thread.
    #pragma unroll
    for (int p = 0; p < 2; ++p) {
        const int u = p * 256 + tid;
        const int tc = u >> 6, e = u & 63;
        half8 a;
        #pragma unroll
        for (int j = 0; j < 8; ++j) a[j] = L[e * 66 + tc * 8 + j];
        // dst: consecutive tid -> consecutive e -> contiguous 16B units
        *reinterpret_cast<half8*>(
            VT8 + ((long)(bh * 256 + (t0 >> 3) + tc) * 64 + e) * 8) = a;
    }
}

// ---------------------------------------------------------------------------
// Pass 1: flash attention partials, KV-split=2. Barrier-free: K and VT8
// fragments are contiguous 16B global loads (L2-resident, channel-spread);
// LDS holds only the per-wave P buffer (same-wave lgkmcnt round trip).
// ---------------------------------------------------------------------------
__global__ __launch_bounds__(256) void attn_part(
    const _Float16* __restrict__ K, const _Float16* __restrict__ VT,
    const float* __restrict__ Qbuf, _Float16* __restrict__ part,
    float* __restrict__ stats)
{
    __shared__ __align__(16) _Float16 Pl[4][16 * PSTR];  // per-wave P: [m][t]

    const int tid  = threadIdx.x;
    const int lane = tid & 63;
    const int wave = tid >> 6;
    const int l15  = lane & 15;
    const int quad = lane >> 4;
    const int bx   = blockIdx.x;          // bh*64 + qt*2 + sp
    const int bh   = bx >> 6;
    const int qt   = (bx >> 1) & 31;
    const int sp   = bx & 1;
    const long base = (long)bh * S_LEN * EMB;
    const int qrow0 = qt * BM + wave * 16;
    // VT8 lane base: + tc*512 + e*8, tc = t/8, e = et*16+l15
    const _Float16* vbase = VT + (long)bh * 256 * 512 + quad * 512 + l15 * 8;

    half8 qf[2];
    #pragma unroll
    for (int ks = 0; ks < 2; ++ks)
        qf[ks] = cvt8(Qbuf + base + (long)(qrow0 + l15) * EMB + ks * 32 + quad * 8);

    float4_t o[4];
    #pragma unroll
    for (int et = 0; et < 4; ++et) o[et] = (float4_t){0.f, 0.f, 0.f, 0.f};
    float m_run[4], l_run[4];
    #pragma unroll
    for (int r = 0; r < 4; ++r) { m_run[r] = M_INIT; l_run[r] = 0.f; }

    const int kt0 = sp * (S_LEN / BN / NSPLIT);          // 8 tiles per split
    for (int kti = 0; kti < S_LEN / BN / NSPLIT; ++kti) {
        const int t0 = (kt0 + kti) * BN;

        // S = Q K^T : 8 n-tiles of 16 cols, fp32 accumulate (K from global)
        float4_t sacc[8];
        #pragma unroll
        for (int nt = 0; nt < 8; ++nt) sacc[nt] = (float4_t){0.f, 0.f, 0.f, 0.f};
        #pragma unroll
        for (int nt = 0; nt < 8; ++nt) {
            const long nrow = base + (long)(t0 + nt * 16 + l15) * EMB;
            #pragma unroll
            for (int ks = 0; ks < 2; ++ks) {
                half8 kf = *reinterpret_cast<const half8*>(
                    K + nrow + ks * 32 + quad * 8);
                sacc[nt] = __builtin_amdgcn_mfma_f32_16x16x32_f16(
                    qf[ks], kf, sacc[nt], 0, 0, 0);
            }
        }

        // online softmax; lane holds rows quad*4+r, cols l15 (+16*nt)
        float mx[4];
        #pragma unroll
        for (int r = 0; r < 4; ++r) {
            mx[r] = sacc[0][r];
            #pragma unroll
            for (int nt = 1; nt < 8; ++nt) mx[r] = fmaxf(mx[r], sacc[nt][r]);
        }
        #pragma unroll
        for (int off = 1; off < 16; off <<= 1)
            #pragma unroll
            for (int r = 0; r < 4; ++r)
                mx[r] = fmaxf(mx[r], __shfl_xor(mx[r], off));

        float alpha[4], rsum[4];
        #pragma unroll
        for (int r = 0; r < 4; ++r) {
            const float mn = fmaxf(m_run[r], mx[r]);
            alpha[r] = __expf(fmaxf(m_run[r] - mn, EXP_CLAMP));
            m_run[r] = mn;
            rsum[r] = 0.f;
        }
        _Float16* Pw = Pl[wave];
        #pragma unroll
        for (int nt = 0; nt < 8; ++nt)
            #pragma unroll
            for (int r = 0; r < 4; ++r) {
                const float p = __expf(fmaxf(sacc[nt][r] - m_run[r], EXP_CLAMP));
                rsum[r] += p;
                Pw[(quad * 4 + r) * PSTR + nt * 16 + l15] = (_Float16)p;
            }
        #pragma unroll
        for (int off = 1; off < 16; off <<= 1)
            #pragma unroll
            for (int r = 0; r < 4; ++r)
                rsum[r] += __shfl_xor(rsum[r], off);
        #pragma unroll
        for (int r = 0; r < 4; ++r)
            l_run[r] = l_run[r] * alpha[r] + rsum[r];
        #pragma unroll
        for (int et = 0; et < 4; ++et)
            #pragma unroll
            for (int r = 0; r < 4; ++r)
                o[et][r] *= alpha[r];
        // no barrier: P write->read is same-wave (compiler lgkmcnt)

        // O += P V : A-frag = P[m=l15][t=ts*32+quad*8+j], B-frag from VT8:
        // addr = vbase + (t0/8 + ts*4)*512 + et*128
        #pragma unroll
        for (int ts = 0; ts < 4; ++ts) {
            half8 pf = *reinterpret_cast<const half8*>(
                &Pw[l15 * PSTR + ts * 32 + quad * 8]);
            const _Float16* vrow = vbase + (long)((t0 >> 3) + ts * 4) * 512;
            #pragma unroll
            for (int et = 0; et < 4; ++et) {
                half8 vf = *reinterpret_cast<const half8*>(vrow + et * 128);
                o[et] = __builtin_amdgcn_mfma_f32_16x16x32_f16(pf, vf, o[et], 0, 0, 0);
            }
        }
    }

    // epilogue: normalized partial O-hat (f16) + (m,l) stats.
    #pragma unroll
    for (int r = 0; r < 4; ++r) {
        const float inv = 1.f / l_run[r];
        const int row = qrow0 + quad * 4 + r;            // 0..2047 within head
        const int R = bh * S_LEN + row;                  // 0..32767 global row
        const long prow = ((long)sp * 32768 + R) * EMB;
        #pragma unroll
        for (int et = 0; et < 4; ++et)
            part[prow + et * 16 + l15] = (_Float16)(o[et][r] * inv);
        if (l15 == 0) {
            stats[sp * 32768 + R] = m_run[r];
            stats[2 * 32768 + sp * 32768 + R] = l_run[r];
        }
    }
}

// ---------------------------------------------------------------------------
// Pass 2: combine the 2 partials. O = w0*Ohat0 + w1*Ohat1, f16-round, f32 store.
// ---------------------------------------------------------------------------
__global__ __launch_bounds__(256) void attn_combine(
    const _Float16* __restrict__ part, const float* __restrict__ stats,
    float* __restrict__ out)
{
    const int gid = blockIdx.x * 256 + threadIdx.x;      // 131072 threads
    const int R  = gid >> 2;
    const int c0 = (gid & 3) * 16;
    const float m0 = stats[R],           m1 = stats[32768 + R];
    const float l0 = stats[2*32768 + R], l1 = stats[3*32768 + R];
    const float M  = fmaxf(m0, m1);
    float w0 = l0 * __expf(fmaxf(m0 - M, EXP_CLAMP));
    float w1 = l1 * __expf(fmaxf(m1 - M, EXP_CLAMP));
    const float rinv = 1.f / (w0 + w1);
    w0 *= rinv; w1 *= rinv;
    const long i0 = (long)R * EMB + c0;
    const long i1 = i0 + (long)32768 * EMB;
    #pragma unroll
    for (int h = 0; h < 2; ++h) {
        half8 a = *reinterpret_cast<const half8*>(part + i0 + h * 8);
        half8 b = *reinterpret_cast<const half8*>(part + i1 + h * 8);
        #pragma unroll
        for (int j = 0; j < 8; ++j)
            out[i0 + h * 8 + j] =
                (float)(_Float16)(w0 * (float)a[j] + w1 * (float)b[j]);
    }
}

// ---------------------------------------------------------------------------
// Buffer plan (no d_ws; all guaranteed-size, stream-ordered):
//   proj Q: d_in[0](f32) -> d_out (f32, f16-rounded, pre-scaled 0.125)
//   proj K: d_in[1](f32) -> d_in[0][0..4MB) as f16 [bh][t][e]
//   proj V: d_in[2](f32) -> d_in[1][0..4MB) as f16 [bh][t][e]
//   vtrans: d_in[1][0..4MB) -> d_in[1][4..8MB) as f16 VT8[bh][t/8][e][t%8]
//   pass1:  K=d_in[0], VT=d_in[1]+4MB, Q=d_out (read-only);
//           partials -> d_in[2] (8MB), stats -> d_in[0]+4MB (512KB)
//   pass2:  combine -> d_out
// ---------------------------------------------------------------------------
extern "C" void kernel_launch(void* const* d_in, const int* in_sizes, int n_in,
                              void* d_out, int out_size, void* d_ws, size_t ws_size,
                              hipStream_t stream) {
    const float* q_in = (const float*)d_in[0];
    const float* k_in = (const float*)d_in[1];
    const float* v_in = (const float*)d_in[2];
    const float* Wq   = (const float*)d_in[3];
    const float* bq   = (const float*)d_in[4];
    const float* Wk   = (const float*)d_in[5];
    const float* bk   = (const float*)d_in[6];
    const float* Wv   = (const float*)d_in[7];
    const float* bv   = (const float*)d_in[8];
    float* out = (float*)d_out;

    _Float16* Kf16  = (_Float16*)d_in[0];
    _Float16* Vf16  = (_Float16*)d_in[1];
    _Float16* VTf16 = Vf16 + (long)2 * 1024 * 1024;      // +4 MB
    _Float16* partb = (_Float16*)d_in[2];
    float*    stats = (float*)((char*)d_in[0] + (4u << 20));

    proj_one<false><<<256, 256, 0, stream>>>(q_in, Wq, bq, out, 0.125f);
    proj_one<true><<<256, 256, 0, stream>>>(k_in, Wk, bk, (void*)Kf16, 1.0f);
    proj_one<true><<<256, 256, 0, stream>>>(v_in, Wv, bv, (void*)Vf16, 1.0f);
    vtrans<<<512, 256, 0, stream>>>(Vf16, VTf16);
    attn_part<<<1024, 256, 0, stream>>>(Kf16, VTf16, out, partb, stats);
    attn_combine<<<512, 256, 0, stream>>>(partb, stats, out);
}

// Round 9
// 159.523 us; speedup vs baseline: 1.5885x; 1.2702x over previous
//
#include <hip/hip_runtime.h>

// Problem constants (B=2, S=2048, H=8, E=64).
// Harness passes f16 tensors upcast to FLOAT32 (in and out). Internally f16
// compute (lossless re-narrowing of f16-origin data), fp32 MFMA accumulation.
#define S_LEN 2048
#define NH    8
#define EMB   64
#define BM    64    // q rows per block (16 per wave)
#define BN    128   // kv tile length
#define NSPLIT 3    // KV splits: 16 bh x 32 qt x 3 = 1536 blocks (3 res/CU x 2)
#define PSTR  136   // padded LDS row stride for P (f16 elems)
#define M_INIT  (-1.0e4f)
#define EXP_CLAMP (-80.0f)

typedef _Float16 half8   __attribute__((ext_vector_type(8)));
typedef float    float4_t __attribute__((ext_vector_type(4)));
typedef float    float8_t __attribute__((ext_vector_type(8)));

__device__ inline half8 cvt8(const float* p) {
    float8_t f = *reinterpret_cast<const float8_t*>(p);
    half8 h;
    #pragma unroll
    for (int j = 0; j < 8; ++j) h[j] = (_Float16)f[j];
    return h;
}

// async global->LDS, 16B per lane; LDS dest = uniform base + lane*16
__device__ inline void gload_lds16(const _Float16* g, _Float16* l) {
    __builtin_amdgcn_global_load_lds(
        (const __attribute__((address_space(1))) void*)g,
        (__attribute__((address_space(3))) void*)l, 16, 0, 0);
}

// ---------------------------------------------------------------------------
// Projection (proven): Out[b,h,s,f] = f16(sum_e X*W + b) * scale, [B,H,S,E].
// ---------------------------------------------------------------------------
template<bool F16OUT>
__global__ __launch_bounds__(256) void proj_one(
    const float* __restrict__ X, const float* __restrict__ W,
    const float* __restrict__ bias, void* __restrict__ OutP, float scale)
{
    const int tid  = threadIdx.x;
    const int lane = tid & 63;
    const int wave = tid >> 6;
    const int l15  = lane & 15;
    const int quad = lane >> 4;
    const int gwave = blockIdx.x * 4 + wave;

    half8 wf[4][2];
    #pragma unroll
    for (int ft = 0; ft < 4; ++ft)
        #pragma unroll
        for (int ks = 0; ks < 2; ++ks)
            wf[ft][ks] = cvt8(W + (ft * 16 + l15) * 64 + ks * 32 + quad * 8);
    float bv[4];
    #pragma unroll
    for (int ft = 0; ft < 4; ++ft) bv[ft] = bias[ft * 16 + l15];

    #pragma unroll
    for (int rt2 = 0; rt2 < 2; ++rt2) {
        const int rt = gwave * 2 + rt2;
        const int arow = rt * 16 + l15;
        half8 xf[2];
        #pragma unroll
        for (int ks = 0; ks < 2; ++ks)
            xf[ks] = cvt8(X + (long)arow * 64 + ks * 32 + quad * 8);
        float4_t acc[4];
        #pragma unroll
        for (int ft = 0; ft < 4; ++ft) {
            acc[ft] = (float4_t){0.f, 0.f, 0.f, 0.f};
            #pragma unroll
            for (int ks = 0; ks < 2; ++ks)
                acc[ft] = __builtin_amdgcn_mfma_f32_16x16x32_f16(
                    xf[ks], wf[ft][ks], acc[ft], 0, 0, 0);
        }
        #pragma unroll
        for (int r = 0; r < 4; ++r) {
            const int row = rt * 16 + quad * 4 + r;     // (b*S+s)*H+h
            const int b = row >> 14;
            const int s = (row >> 3) & 2047;
            const int h = row & 7;
            const long orow = ((long)(b * NH + h) * S_LEN + s) * EMB;
            #pragma unroll
            for (int ft = 0; ft < 4; ++ft) {
                const _Float16 v =
                    (_Float16)(acc[ft][r] + bv[ft]) * (_Float16)scale;
                if (F16OUT) ((_Float16*)OutP)[orow + ft * 16 + l15] = v;
                else        ((float*)OutP)[orow + ft * 16 + l15] = (float)v;
            }
        }
    }
}

// ---------------------------------------------------------------------------
// K relayout: [bh][t][e] -> KT8[bh][ec=e/8][t][e%8]. Pure index shuffle (the
// 8 e-consecutive elems of a unit are contiguous in the source). Writes are
// perfectly coalesced (unit id == output offset).
// ---------------------------------------------------------------------------
__global__ __launch_bounds__(256) void ktrans(
    const _Float16* __restrict__ Kin, _Float16* __restrict__ KT8)
{
    const int id = blockIdx.x * 256 + threadIdx.x;   // 262144 units of 8
    const int t  = id & 2047;
    const int be = id >> 11;                         // bh*8 + ec
    const int bh = be >> 3, ec = be & 7;
    half8 a = *reinterpret_cast<const half8*>(
        Kin + ((long)bh * S_LEN + t) * EMB + ec * 8);
    *reinterpret_cast<half8*>(KT8 + (long)id * 8) = a;
}

// ---------------------------------------------------------------------------
// V transpose into VT8[bh][t/8][e][t%8] (verified R8). A PV B-fragment is one
// contiguous 16B unit; a BN-tile is one contiguous 16KB range.
// ---------------------------------------------------------------------------
__global__ __launch_bounds__(256) void vtrans(
    const _Float16* __restrict__ Vin, _Float16* __restrict__ VT8)
{
    __shared__ _Float16 L[64 * 66];
    const int tid = threadIdx.x;
    const int bh  = blockIdx.x >> 5;
    const int t0  = (blockIdx.x & 31) * 64;
    const _Float16* src = Vin + ((long)bh * S_LEN + t0) * EMB;
    #pragma unroll
    for (int p = 0; p < 2; ++p) {
        const int chunk = p * 256 + tid;
        const int tl = chunk >> 3, e0 = (chunk & 7) * 8;
        half8 v = *reinterpret_cast<const half8*>(src + tl * EMB + e0);
        #pragma unroll
        for (int j = 0; j < 8; ++j) L[(e0 + j) * 66 + tl] = v[j];
    }
    __syncthreads();
    #pragma unroll
    for (int p = 0; p < 2; ++p) {
        const int u = p * 256 + tid;
        const int tc = u >> 6, e = u & 63;
        half8 a;
        #pragma unroll
        for (int j = 0; j < 8; ++j) a[j] = L[e * 66 + tc * 8 + j];
        *reinterpret_cast<half8*>(
            VT8 + ((long)(bh * 256 + (t0 >> 3) + tc) * 64 + e) * 8) = a;
    }
}

// ---------------------------------------------------------------------------
// Pass 1: flash attention partials, KV-split=3. K and V tiles staged in LDS
// via global_load_lds (16B) once per block-iter and shared by all 4 waves
// (4x less VMEM than per-wave global loads; no L1 thrash). KT8/VT8 LDS
// images give conflict-free ds_read_b128 fragments (bank = 4*(l15&7), 8
// dwords/bank = minimum). Softmax/P/PV identical to the passing R8 kernel.
// ---------------------------------------------------------------------------
__global__ __launch_bounds__(256) void attn_part(
    const _Float16* __restrict__ KT, const _Float16* __restrict__ VT,
    const float* __restrict__ Qbuf,
    _Float16* __restrict__ p0, _Float16* __restrict__ p1,
    _Float16* __restrict__ p2, float* __restrict__ stats)
{
    __shared__ __align__(16) _Float16 Kb[8 * 128 * 8];   // 16 KB [ec][tl][ej]
    __shared__ __align__(16) _Float16 Vb[16 * 64 * 8];   // 16 KB [tc][e][tj]
    __shared__ __align__(16) _Float16 Pl[4][16 * PSTR];  // 17.4 KB per-wave P

    const int tid  = threadIdx.x;
    const int lane = tid & 63;
    const int wave = tid >> 6;
    const int l15  = lane & 15;
    const int quad = lane >> 4;
    const int bx   = blockIdx.x;
    const int bh   = bx / (32 * NSPLIT);
    const int rem  = bx % (32 * NSPLIT);
    const int qt   = rem / NSPLIT;
    const int sp   = rem % NSPLIT;
    const long base = (long)bh * S_LEN * EMB;
    const int qrow0 = qt * BM + wave * 16;

    const _Float16* kg = KT + (long)bh * 8 * S_LEN * 8;  // head base in KT8

    half8 qf[2];
    #pragma unroll
    for (int ks = 0; ks < 2; ++ks)
        qf[ks] = cvt8(Qbuf + base + (long)(qrow0 + l15) * EMB + ks * 32 + quad * 8);

    float4_t o[4];
    #pragma unroll
    for (int et = 0; et < 4; ++et) o[et] = (float4_t){0.f, 0.f, 0.f, 0.f};
    float m_run[4], l_run[4];
    #pragma unroll
    for (int r = 0; r < 4; ++r) { m_run[r] = M_INIT; l_run[r] = 0.f; }

    const int kb = (sp * 16) / NSPLIT, ke = ((sp + 1) * 16) / NSPLIT; // 5/5/6
    for (int kt = kb; kt < ke; ++kt) {
        if (kt > kb) __syncthreads();     // prev-iter consumers done
        const int t0 = kt * BN;
        // stage K tile: 1024 units of 16B; per-thread 4 (ec = u>>7, tl = u&127)
        #pragma unroll
        for (int rr = 0; rr < 4; ++rr) {
            const int u = rr * 256 + tid;
            const int ec = u >> 7, tl = u & 127;
            gload_lds16(kg + ((long)ec * S_LEN + t0 + tl) * 8, Kb + u * 8);
        }
        // stage V tile: contiguous 16KB in VT8
        const _Float16* vg = VT + ((long)bh * 256 + (t0 >> 3)) * 512;
        #pragma unroll
        for (int rr = 0; rr < 4; ++rr) {
            const int u = rr * 256 + tid;
            gload_lds16(vg + u * 8, Vb + u * 8);
        }
        __syncthreads();                  // drains vmcnt -> tiles visible

        // S = Q K^T : 8 n-tiles of 16 cols, fp32 accumulate (K from LDS)
        float4_t sacc[8];
        #pragma unroll
        for (int nt = 0; nt < 8; ++nt) sacc[nt] = (float4_t){0.f, 0.f, 0.f, 0.f};
        #pragma unroll
        for (int nt = 0; nt < 8; ++nt)
            #pragma unroll
            for (int ks = 0; ks < 2; ++ks) {
                half8 kf = *reinterpret_cast<const half8*>(
                    Kb + (ks * 4 + quad) * 1024 + (nt * 16 + l15) * 8);
                sacc[nt] = __builtin_amdgcn_mfma_f32_16x16x32_f16(
                    qf[ks], kf, sacc[nt], 0, 0, 0);
            }

        // online softmax; lane holds rows quad*4+r, cols l15 (+16*nt)
        float mx[4];
        #pragma unroll
        for (int r = 0; r < 4; ++r) {
            mx[r] = sacc[0][r];
            #pragma unroll
            for (int nt = 1; nt < 8; ++nt) mx[r] = fmaxf(mx[r], sacc[nt][r]);
        }
        #pragma unroll
        for (int off = 1; off < 16; off <<= 1)
            #pragma unroll
            for (int r = 0; r < 4; ++r)
                mx[r] = fmaxf(mx[r], __shfl_xor(mx[r], off));

        float alpha[4], rsum[4];
        #pragma unroll
        for (int r = 0; r < 4; ++r) {
            const float mn = fmaxf(m_run[r], mx[r]);
            alpha[r] = __expf(fmaxf(m_run[r] - mn, EXP_CLAMP));
            m_run[r] = mn;
            rsum[r] = 0.f;
        }
        _Float16* Pw = Pl[wave];
        #pragma unroll
        for (int nt = 0; nt < 8; ++nt)
            #pragma unroll
            for (int r = 0; r < 4; ++r) {
                const float p = __expf(fmaxf(sacc[nt][r] - m_run[r], EXP_CLAMP));
                rsum[r] += p;
                Pw[(quad * 4 + r) * PSTR + nt * 16 + l15] = (_Float16)p;
            }
        #pragma unroll
        for (int off = 1; off < 16; off <<= 1)
            #pragma unroll
            for (int r = 0; r < 4; ++r)
                rsum[r] += __shfl_xor(rsum[r], off);
        #pragma unroll
        for (int r = 0; r < 4; ++r)
            l_run[r] = l_run[r] * alpha[r] + rsum[r];
        #pragma unroll
        for (int et = 0; et < 4; ++et)
            #pragma unroll
            for (int r = 0; r < 4; ++r)
                o[et][r] *= alpha[r];
        // no barrier: P write->read is same-wave (compiler lgkmcnt)

        // O += P V : A-frag = P[m=l15][t=ts*32+quad*8+j], B-frag from Vb LDS
        #pragma unroll
        for (int ts = 0; ts < 4; ++ts) {
            half8 pf = *reinterpret_cast<const half8*>(
                &Pw[l15 * PSTR + ts * 32 + quad * 8]);
            #pragma unroll
            for (int et = 0; et < 4; ++et) {
                half8 vf = *reinterpret_cast<const half8*>(
                    Vb + (ts * 4 + quad) * 512 + (et * 16 + l15) * 8);
                o[et] = __builtin_amdgcn_mfma_f32_16x16x32_f16(pf, vf, o[et], 0, 0, 0);
            }
        }
    }

    // epilogue: normalized partial O-hat (f16) + (m,l) stats.
    _Float16* pp = (sp == 0) ? p0 : (sp == 1) ? p1 : p2;
    #pragma unroll
    for (int r = 0; r < 4; ++r) {
        const float inv = 1.f / l_run[r];
        const int row = qrow0 + quad * 4 + r;            // 0..2047 within head
        const int R = bh * S_LEN + row;                  // 0..32767 global row
        #pragma unroll
        for (int et = 0; et < 4; ++et)
            pp[(long)R * EMB + et * 16 + l15] = (_Float16)(o[et][r] * inv);
        if (l15 == 0) {
            stats[sp * 32768 + R] = m_run[r];
            stats[(NSPLIT + sp) * 32768 + R] = l_run[r];
        }
    }
}

// ---------------------------------------------------------------------------
// Pass 2: combine the 3 partials. O = sum w_i*Ohat_i, f16-round, f32 store.
// ---------------------------------------------------------------------------
__global__ __launch_bounds__(256) void attn_combine(
    const _Float16* __restrict__ p0, const _Float16* __restrict__ p1,
    const _Float16* __restrict__ p2, const float* __restrict__ stats,
    float* __restrict__ out)
{
    const int gid = blockIdx.x * 256 + threadIdx.x;      // 131072 threads
    const int R  = gid >> 2;
    const int c0 = (gid & 3) * 16;
    const float m0 = stats[R], m1 = stats[32768 + R], m2 = stats[2 * 32768 + R];
    const float l0 = stats[3 * 32768 + R], l1 = stats[4 * 32768 + R],
                l2 = stats[5 * 32768 + R];
    const float M = fmaxf(fmaxf(m0, m1), m2);
    float w0 = l0 * __expf(fmaxf(m0 - M, EXP_CLAMP));
    float w1 = l1 * __expf(fmaxf(m1 - M, EXP_CLAMP));
    float w2 = l2 * __expf(fmaxf(m2 - M, EXP_CLAMP));
    const float rinv = 1.f / (w0 + w1 + w2);
    w0 *= rinv; w1 *= rinv; w2 *= rinv;
    const long i0 = (long)R * EMB + c0;
    #pragma unroll
    for (int h = 0; h < 2; ++h) {
        half8 a = *reinterpret_cast<const half8*>(p0 + i0 + h * 8);
        half8 b = *reinterpret_cast<const half8*>(p1 + i0 + h * 8);
        half8 c = *reinterpret_cast<const half8*>(p2 + i0 + h * 8);
        #pragma unroll
        for (int j = 0; j < 8; ++j)
            out[i0 + h * 8 + j] = (float)(_Float16)(
                w0 * (float)a[j] + w1 * (float)b[j] + w2 * (float)c[j]);
    }
}

// ---------------------------------------------------------------------------
// Buffer plan (no d_ws; all guaranteed-size, stream-ordered):
//   projQ:  d_in[0](f32) -> d_out (f32, f16-rounded, pre-scaled 0.125)
//   projK:  d_in[1](f32) -> Knat = d_in[0][4,8MB) f16   (q_in dead)
//   projV:  d_in[2](f32) -> Vnat = d_in[1][0,4MB) f16   (k_in dead)
//   ktrans: Knat -> KT8 = d_in[0][0,4MB)                (q_in dead)
//   vtrans: Vnat -> VT8 = d_in[1][4,8MB)
//   pass1:  partials p0,p1 -> d_in[2][0,8MB) (v_in dead),
//           p2 -> Vnat region (dead after vtrans),
//           stats -> d_in[0][4,4.75MB) (Knat dead after ktrans)
//   pass2:  combine -> d_out (Q dead)
// ---------------------------------------------------------------------------
extern "C" void kernel_launch(void* const* d_in, const int* in_sizes, int n_in,
                              void* d_out, int out_size, void* d_ws, size_t ws_size,
                              hipStream_t stream) {
    const float* q_in = (const float*)d_in[0];
    const float* k_in = (const float*)d_in[1];
    const float* v_in = (const float*)d_in[2];
    const float* Wq   = (const float*)d_in[3];
    const float* bq   = (const float*)d_in[4];
    const float* Wk   = (const float*)d_in[5];
    const float* bk   = (const float*)d_in[6];
    const float* Wv   = (const float*)d_in[7];
    const float* bv   = (const float*)d_in[8];
    float* out = (float*)d_out;

    _Float16* KT8   = (_Float16*)d_in[0];
    _Float16* Knat  = (_Float16*)((char*)d_in[0] + (4u << 20));
    float*    stats = (float*)((char*)d_in[0] + (4u << 20));   // Knat dead then
    _Float16* Vnat  = (_Float16*)d_in[1];
    _Float16* VT8   = (_Float16*)((char*)d_in[1] + (4u << 20));
    _Float16* part0 = (_Float16*)d_in[2];
    _Float16* part1 = part0 + (long)2 * 1024 * 1024;           // +4 MB
    _Float16* part2 = Vnat;                                    // dead post-vtrans

    proj_one<false><<<256, 256, 0, stream>>>(q_in, Wq, bq, out, 0.125f);
    proj_one<true><<<256, 256, 0, stream>>>(k_in, Wk, bk, (void*)Knat, 1.0f);
    proj_one<true><<<256, 256, 0, stream>>>(v_in, Wv, bv, (void*)Vnat, 1.0f);
    ktrans<<<1024, 256, 0, stream>>>(Knat, KT8);
    vtrans<<<512, 256, 0, stream>>>(Vnat, VT8);
    attn_part<<<16 * 32 * NSPLIT, 256, 0, stream>>>(KT8, VT8, out,
                                                    part0, part1, part2, stats);
    attn_combine<<<512, 256, 0, stream>>>(part0, part1, part2, stats, out);
}

// Round 10
// 140.285 us; speedup vs baseline: 1.8064x; 1.1371x over previous
//
#include <hip/hip_runtime.h>

// Problem constants (B=2, S=2048, H=8, E=64).
// Harness passes f16 tensors upcast to FLOAT32 (in and out). Internally f16
// compute (lossless re-narrowing of f16-origin data), fp32 MFMA accumulation.
#define S_LEN 2048
#define NH    8
#define EMB   64
#define BM    64    // q rows per block (16 per wave)
#define BN    128   // kv tile length
#define NSPLIT 3    // KV splits: 16 bh x 32 qt x 3 = 1536 blocks
#define PSTR  136   // padded LDS row stride for P (f16 elems)
#define M_INIT  (-1.0e4f)
#define EXP_CLAMP (-80.0f)

typedef _Float16 half8   __attribute__((ext_vector_type(8)));
typedef _Float16 half4   __attribute__((ext_vector_type(4)));
typedef float    float4_t __attribute__((ext_vector_type(4)));
typedef float    float8_t __attribute__((ext_vector_type(8)));

__device__ inline half8 cvt8(const float* p) {
    float8_t f = *reinterpret_cast<const float8_t*>(p);
    half8 h;
    #pragma unroll
    for (int j = 0; j < 8; ++j) h[j] = (_Float16)f[j];
    return h;
}

// async global->LDS, 16B per lane; LDS dest = uniform base + lane*16
__device__ inline void gload_lds16(const _Float16* g, _Float16* l) {
    __builtin_amdgcn_global_load_lds(
        (const __attribute__((address_space(1))) void*)g,
        (__attribute__((address_space(3))) void*)l, 16, 0, 0);
}

// ---------------------------------------------------------------------------
// Launch 1: Q projection -> d_out f32 [B,H,S,E], pre-scaled by 0.125.
// (Only d_out is writable while q/k/v inputs are all still live.)
// ---------------------------------------------------------------------------
__global__ __launch_bounds__(256) void proj_q(
    const float* __restrict__ X, const float* __restrict__ W,
    const float* __restrict__ bias, float* __restrict__ Out)
{
    const int tid  = threadIdx.x;
    const int lane = tid & 63;
    const int wave = tid >> 6;
    const int l15  = lane & 15;
    const int quad = lane >> 4;
    const int gwave = blockIdx.x * 4 + wave;

    half8 wf[4][2];
    #pragma unroll
    for (int ft = 0; ft < 4; ++ft)
        #pragma unroll
        for (int ks = 0; ks < 2; ++ks)
            wf[ft][ks] = cvt8(W + (ft * 16 + l15) * 64 + ks * 32 + quad * 8);
    float bv[4];
    #pragma unroll
    for (int ft = 0; ft < 4; ++ft) bv[ft] = bias[ft * 16 + l15];

    #pragma unroll
    for (int rt2 = 0; rt2 < 2; ++rt2) {
        const int rt = gwave * 2 + rt2;
        const int arow = rt * 16 + l15;
        half8 xf[2];
        #pragma unroll
        for (int ks = 0; ks < 2; ++ks)
            xf[ks] = cvt8(X + (long)arow * 64 + ks * 32 + quad * 8);
        float4_t acc[4];
        #pragma unroll
        for (int ft = 0; ft < 4; ++ft) {
            acc[ft] = (float4_t){0.f, 0.f, 0.f, 0.f};
            #pragma unroll
            for (int ks = 0; ks < 2; ++ks)
                acc[ft] = __builtin_amdgcn_mfma_f32_16x16x32_f16(
                    xf[ks], wf[ft][ks], acc[ft], 0, 0, 0);
        }
        #pragma unroll
        for (int r = 0; r < 4; ++r) {
            const int row = rt * 16 + quad * 4 + r;     // (b*S+s)*H+h
            const int b = row >> 14;
            const int s = (row >> 3) & 2047;
            const int h = row & 7;
            const long orow = ((long)(b * NH + h) * S_LEN + s) * EMB;
            #pragma unroll
            for (int ft = 0; ft < 4; ++ft) {
                const _Float16 v =
                    (_Float16)(acc[ft][r] + bv[ft]) * (_Float16)0.125f;
                Out[orow + ft * 16 + l15] = (float)v;
            }
        }
    }
}

// ---------------------------------------------------------------------------
// Launch 2: K and V projections fused, writing attention-ready layouts
// DIRECTLY (no separate relayout kernels):
//   seg 0: K -> KT8[bh][f/8][s][f%8]
//   seg 1: V -> VT8[bh][s/8][f][s%8]
// ---------------------------------------------------------------------------
__global__ __launch_bounds__(256) void proj_kv(
    const float* __restrict__ k_in, const float* __restrict__ v_in,
    const float* __restrict__ Wk, const float* __restrict__ bk,
    const float* __restrict__ Wv, const float* __restrict__ bv_,
    _Float16* __restrict__ KT8, _Float16* __restrict__ VT8)
{
    const int seg = blockIdx.x >> 8;          // 0=K, 1=V
    const int bid = blockIdx.x & 255;
    const float* X    = seg ? v_in : k_in;
    const float* W    = seg ? Wv : Wk;
    const float* bias = seg ? bv_ : bk;

    const int tid  = threadIdx.x;
    const int lane = tid & 63;
    const int wave = tid >> 6;
    const int l15  = lane & 15;
    const int quad = lane >> 4;
    const int gwave = bid * 4 + wave;

    half8 wf[4][2];
    #pragma unroll
    for (int ft = 0; ft < 4; ++ft)
        #pragma unroll
        for (int ks = 0; ks < 2; ++ks)
            wf[ft][ks] = cvt8(W + (ft * 16 + l15) * 64 + ks * 32 + quad * 8);
    float bv[4];
    #pragma unroll
    for (int ft = 0; ft < 4; ++ft) bv[ft] = bias[ft * 16 + l15];

    #pragma unroll
    for (int rt2 = 0; rt2 < 2; ++rt2) {
        const int rt = gwave * 2 + rt2;
        const int arow = rt * 16 + l15;
        half8 xf[2];
        #pragma unroll
        for (int ks = 0; ks < 2; ++ks)
            xf[ks] = cvt8(X + (long)arow * 64 + ks * 32 + quad * 8);
        float4_t acc[4];
        #pragma unroll
        for (int ft = 0; ft < 4; ++ft) {
            acc[ft] = (float4_t){0.f, 0.f, 0.f, 0.f};
            #pragma unroll
            for (int ks = 0; ks < 2; ++ks)
                acc[ft] = __builtin_amdgcn_mfma_f32_16x16x32_f16(
                    xf[ks], wf[ft][ks], acc[ft], 0, 0, 0);
        }
        #pragma unroll
        for (int r = 0; r < 4; ++r) {
            const int row = rt * 16 + quad * 4 + r;     // (b*S+s)*H+h
            const int b = row >> 14;
            const int s = (row >> 3) & 2047;
            const int h = row & 7;
            const int bh = b * NH + h;
            #pragma unroll
            for (int ft = 0; ft < 4; ++ft) {
                const _Float16 v = (_Float16)(acc[ft][r] + bv[ft]);
                const int f = ft * 16 + l15;
                if (seg == 0)
                    KT8[(((long)bh * 8 + (f >> 3)) * S_LEN + s) * 8 + (f & 7)] = v;
                else
                    VT8[(((long)bh * 256 + (s >> 3)) * 64 + f) * 8 + (s & 7)] = v;
            }
        }
    }
}

// ---------------------------------------------------------------------------
// Launch 3: flash attention partials, KV-split=3, S^T orientation.
// K/V tiles staged in LDS via global_load_lds (16B) and shared by all waves.
// S^T = K·Q^T (operand swap; fragment reads unchanged): each lane owns ONE
// q-row (l15) -> softmax reduce = 31 local ops + 2 shuffle rounds; m/l are
// scalars; P stored as 8x ds_write_b64 (4 consecutive t per write).
// ---------------------------------------------------------------------------
__global__ __launch_bounds__(256) void attn_part(
    const _Float16* __restrict__ KT, const _Float16* __restrict__ VT,
    const float* __restrict__ Qbuf,
    _Float16* __restrict__ p0, _Float16* __restrict__ p1,
    _Float16* __restrict__ p2, float* __restrict__ stats)
{
    __shared__ __align__(16) _Float16 Kb[8 * 128 * 8];   // 16 KB [ec][tl][ej]
    __shared__ __align__(16) _Float16 Vb[16 * 64 * 8];   // 16 KB [tc][e][tj]
    __shared__ __align__(16) _Float16 Pl[4][16 * PSTR];  // per-wave P: [q][t]

    const int tid  = threadIdx.x;
    const int lane = tid & 63;
    const int wave = tid >> 6;
    const int l15  = lane & 15;
    const int quad = lane >> 4;
    const int bx   = blockIdx.x;
    const int bh   = bx / (32 * NSPLIT);
    const int rem  = bx % (32 * NSPLIT);
    const int qt   = rem / NSPLIT;
    const int sp   = rem % NSPLIT;
    const long base = (long)bh * S_LEN * EMB;
    const int qrow0 = qt * BM + wave * 16;

    const _Float16* kg = KT + (long)bh * 8 * S_LEN * 8;  // head base in KT8

    half8 qf[2];   // B-frag now: Q[n = q-row l15][e = ks*32+quad*8+j]
    #pragma unroll
    for (int ks = 0; ks < 2; ++ks)
        qf[ks] = cvt8(Qbuf + base + (long)(qrow0 + l15) * EMB + ks * 32 + quad * 8);

    float4_t o[4];
    #pragma unroll
    for (int et = 0; et < 4; ++et) o[et] = (float4_t){0.f, 0.f, 0.f, 0.f};
    float m_run = M_INIT, l_run = 0.f;    // this lane's q-row = l15

    const int kb = (sp * 16) / NSPLIT, ke = ((sp + 1) * 16) / NSPLIT; // 5/5/6
    for (int kt = kb; kt < ke; ++kt) {
        if (kt > kb) __syncthreads();     // prev-iter consumers done
        const int t0 = kt * BN;
        #pragma unroll
        for (int rr = 0; rr < 4; ++rr) {  // K tile: [ec][tl][ej]
            const int u = rr * 256 + tid;
            const int ec = u >> 7, tl = u & 127;
            gload_lds16(kg + ((long)ec * S_LEN + t0 + tl) * 8, Kb + u * 8);
        }
        const _Float16* vg = VT + ((long)bh * 256 + (t0 >> 3)) * 512;
        #pragma unroll
        for (int rr = 0; rr < 4; ++rr) {  // V tile: contiguous 16 KB
            const int u = rr * 256 + tid;
            gload_lds16(vg + u * 8, Vb + u * 8);
        }
        __syncthreads();                  // drains vmcnt -> tiles visible

        // S^T = K Q^T : D[row=quad*4+r -> t][col=l15 -> q-row]
        float4_t sacc[8];
        #pragma unroll
        for (int nt = 0; nt < 8; ++nt) sacc[nt] = (float4_t){0.f, 0.f, 0.f, 0.f};
        #pragma unroll
        for (int nt = 0; nt < 8; ++nt)
            #pragma unroll
            for (int ks = 0; ks < 2; ++ks) {
                half8 kf = *reinterpret_cast<const half8*>(   // A: K[m=t][e]
                    Kb + (ks * 4 + quad) * 1024 + (nt * 16 + l15) * 8);
                sacc[nt] = __builtin_amdgcn_mfma_f32_16x16x32_f16(
                    kf, qf[ks], sacc[nt], 0, 0, 0);
            }

        // softmax for q-row l15: 32 local values (t = nt*16 + quad*4 + r)
        float mx = sacc[0][0];
        #pragma unroll
        for (int nt = 0; nt < 8; ++nt)
            #pragma unroll
            for (int r = 0; r < 4; ++r) mx = fmaxf(mx, sacc[nt][r]);
        mx = fmaxf(mx, __shfl_xor(mx, 16));
        mx = fmaxf(mx, __shfl_xor(mx, 32));

        const float mn = fmaxf(m_run, mx);
        const float alpha = __expf(fmaxf(m_run - mn, EXP_CLAMP));
        m_run = mn;

        _Float16* Pw = Pl[wave];
        float rsum = 0.f;
        #pragma unroll
        for (int nt = 0; nt < 8; ++nt) {
            half4 ph;
            #pragma unroll
            for (int r = 0; r < 4; ++r) {
                const float p = __expf(sacc[nt][r] - m_run);
                rsum += p;
                ph[r] = (_Float16)p;
            }
            // P[q=l15][t = nt*16 + quad*4 + 0..3] : one b64 write
            *reinterpret_cast<half4*>(&Pw[l15 * PSTR + nt * 16 + quad * 4]) = ph;
        }
        rsum += __shfl_xor(rsum, 16);
        rsum += __shfl_xor(rsum, 32);
        l_run = l_run * alpha + rsum;

        // rescale O (rows quad*4+r need alpha of lane quad*4+r)
        #pragma unroll
        for (int r = 0; r < 4; ++r) {
            const float ar = __shfl(alpha, quad * 4 + r);
            #pragma unroll
            for (int et = 0; et < 4; ++et) o[et][r] *= ar;
        }
        // no barrier: P write->read is intra-wave (compiler lgkmcnt)

        // O += P V : A-frag = P[m=l15][t=ts*32+quad*8+j], B-frag from Vb LDS
        #pragma unroll
        for (int ts = 0; ts < 4; ++ts) {
            half8 pf = *reinterpret_cast<const half8*>(
                &Pw[l15 * PSTR + ts * 32 + quad * 8]);
            #pragma unroll
            for (int et = 0; et < 4; ++et) {
                half8 vf = *reinterpret_cast<const half8*>(
                    Vb + (ts * 4 + quad) * 512 + (et * 16 + l15) * 8);
                o[et] = __builtin_amdgcn_mfma_f32_16x16x32_f16(pf, vf, o[et], 0, 0, 0);
            }
        }
    }

    // epilogue: normalized partial O-hat (f16) + (m,l) stats.
    _Float16* pp = (sp == 0) ? p0 : (sp == 1) ? p1 : p2;
    #pragma unroll
    for (int r = 0; r < 4; ++r) {
        const float lr = __shfl(l_run, quad * 4 + r);    // row quad*4+r's sum
        const float inv = 1.f / lr;
        const int row = qrow0 + quad * 4 + r;            // 0..2047 within head
        const int R = bh * S_LEN + row;                  // 0..32767 global row
        #pragma unroll
        for (int et = 0; et < 4; ++et)
            pp[(long)R * EMB + et * 16 + l15] = (_Float16)(o[et][r] * inv);
    }
    if (lane < 16) {                                     // lane i owns q-row i
        const int R = bh * S_LEN + qrow0 + lane;
        stats[sp * 32768 + R] = m_run;
        stats[(NSPLIT + sp) * 32768 + R] = l_run;
    }
}

// ---------------------------------------------------------------------------
// Launch 4: combine the 3 partials. O = sum w_i*Ohat_i, f16-round, f32 store.
// ---------------------------------------------------------------------------
__global__ __launch_bounds__(256) void attn_combine(
    const _Float16* __restrict__ p0, const _Float16* __restrict__ p1,
    const _Float16* __restrict__ p2, const float* __restrict__ stats,
    float* __restrict__ out)
{
    const int gid = blockIdx.x * 256 + threadIdx.x;      // 131072 threads
    const int R  = gid >> 2;
    const int c0 = (gid & 3) * 16;
    const float m0 = stats[R], m1 = stats[32768 + R], m2 = stats[2 * 32768 + R];
    const float l0 = stats[3 * 32768 + R], l1 = stats[4 * 32768 + R],
                l2 = stats[5 * 32768 + R];
    const float M = fmaxf(fmaxf(m0, m1), m2);
    float w0 = l0 * __expf(fmaxf(m0 - M, EXP_CLAMP));
    float w1 = l1 * __expf(fmaxf(m1 - M, EXP_CLAMP));
    float w2 = l2 * __expf(fmaxf(m2 - M, EXP_CLAMP));
    const float rinv = 1.f / (w0 + w1 + w2);
    w0 *= rinv; w1 *= rinv; w2 *= rinv;
    const long i0 = (long)R * EMB + c0;
    #pragma unroll
    for (int h = 0; h < 2; ++h) {
        half8 a = *reinterpret_cast<const half8*>(p0 + i0 + h * 8);
        half8 b = *reinterpret_cast<const half8*>(p1 + i0 + h * 8);
        half8 c = *reinterpret_cast<const half8*>(p2 + i0 + h * 8);
        #pragma unroll
        for (int j = 0; j < 8; ++j)
            out[i0 + h * 8 + j] = (float)(_Float16)(
                w0 * (float)a[j] + w1 * (float)b[j] + w2 * (float)c[j]);
    }
}

// ---------------------------------------------------------------------------
// 4 launches (was 7). Buffer plan (no d_ws; stream-ordered liveness):
//   L1 proj_q:  d_in[0](f32) -> d_out (f32, f16-rounded, pre-scaled)
//   L2 proj_kv: d_in[1] -> KT8 = d_in[0][0,4MB); d_in[2] -> VT8 = d_in[0][4,8MB)
//               (q_in dead after L1; k_in/v_in still pristine sources)
//   L3 attn_part: reads KT8/VT8/d_out; p0,p1 -> d_in[2][0,8MB) (v_in dead),
//               p2 -> d_in[1][0,4MB) (k_in dead), stats -> d_in[1][4,4.75MB)
//   L4 combine -> d_out (Q dead)
// ---------------------------------------------------------------------------
extern "C" void kernel_launch(void* const* d_in, const int* in_sizes, int n_in,
                              void* d_out, int out_size, void* d_ws, size_t ws_size,
                              hipStream_t stream) {
    const float* q_in = (const float*)d_in[0];
    const float* k_in = (const float*)d_in[1];
    const float* v_in = (const float*)d_in[2];
    const float* Wq   = (const float*)d_in[3];
    const float* bq   = (const float*)d_in[4];
    const float* Wk   = (const float*)d_in[5];
    const float* bk   = (const float*)d_in[6];
    const float* Wv   = (const float*)d_in[7];
    const float* bv   = (const float*)d_in[8];
    float* out = (float*)d_out;

    _Float16* KT8   = (_Float16*)d_in[0];
    _Float16* VT8   = (_Float16*)((char*)d_in[0] + (4u << 20));
    _Float16* part0 = (_Float16*)d_in[2];
    _Float16* part1 = part0 + (long)2 * 1024 * 1024;           // +4 MB
    _Float16* part2 = (_Float16*)d_in[1];
    float*    stats = (float*)((char*)d_in[1] + (4u << 20));

    proj_q<<<256, 256, 0, stream>>>(q_in, Wq, bq, out);
    proj_kv<<<512, 256, 0, stream>>>(k_in, v_in, Wk, bk, Wv, bv, KT8, VT8);
    attn_part<<<16 * 32 * NSPLIT, 256, 0, stream>>>(KT8, VT8, out,
                                                    part0, part1, part2, stats);
    attn_combine<<<512, 256, 0, stream>>>(part0, part1, part2, stats, out);
}

// Round 11
// 139.421 us; speedup vs baseline: 1.8175x; 1.0062x over previous
//
#include <hip/hip_runtime.h>

// Problem constants (B=2, S=2048, H=8, E=64).
// Harness passes f16 tensors upcast to FLOAT32 (in and out). Internally f16
// compute (lossless re-narrowing of f16-origin data), fp32 MFMA accumulation.
#define S_LEN 2048
#define NH    8
#define EMB   64
#define BM    64    // q rows per block (16 per wave)
#define BN    64    // kv tile length (64 -> 25KB LDS -> 6 blocks/CU)
#define NKT   (S_LEN / BN)          // 32 kv tiles
#define NSPLIT 3    // KV splits: 16 bh x 32 qt x 3 = 1536 blocks = 6/CU exactly
#define PSTR  72    // padded LDS row stride for P (f16 elems, 144B: 16B-aligned)
#define M_INIT  (-1.0e4f)
#define EXP_CLAMP (-80.0f)

typedef _Float16 half8   __attribute__((ext_vector_type(8)));
typedef _Float16 half4   __attribute__((ext_vector_type(4)));
typedef float    float4_t __attribute__((ext_vector_type(4)));
typedef float    float8_t __attribute__((ext_vector_type(8)));

__device__ inline half8 cvt8(const float* p) {
    float8_t f = *reinterpret_cast<const float8_t*>(p);
    half8 h;
    #pragma unroll
    for (int j = 0; j < 8; ++j) h[j] = (_Float16)f[j];
    return h;
}

// async global->LDS, 16B per lane; LDS dest = uniform base + lane*16
__device__ inline void gload_lds16(const _Float16* g, _Float16* l) {
    __builtin_amdgcn_global_load_lds(
        (const __attribute__((address_space(1))) void*)g,
        (__attribute__((address_space(3))) void*)l, 16, 0, 0);
}

// ---------------------------------------------------------------------------
// Launch 1: Q projection -> d_out f32 [B,H,S,E], pre-scaled by 0.125.
// ---------------------------------------------------------------------------
__global__ __launch_bounds__(256) void proj_q(
    const float* __restrict__ X, const float* __restrict__ W,
    const float* __restrict__ bias, float* __restrict__ Out)
{
    const int tid  = threadIdx.x;
    const int lane = tid & 63;
    const int wave = tid >> 6;
    const int l15  = lane & 15;
    const int quad = lane >> 4;
    const int gwave = blockIdx.x * 4 + wave;

    half8 wf[4][2];
    #pragma unroll
    for (int ft = 0; ft < 4; ++ft)
        #pragma unroll
        for (int ks = 0; ks < 2; ++ks)
            wf[ft][ks] = cvt8(W + (ft * 16 + l15) * 64 + ks * 32 + quad * 8);
    float bv[4];
    #pragma unroll
    for (int ft = 0; ft < 4; ++ft) bv[ft] = bias[ft * 16 + l15];

    #pragma unroll
    for (int rt2 = 0; rt2 < 2; ++rt2) {
        const int rt = gwave * 2 + rt2;
        const int arow = rt * 16 + l15;
        half8 xf[2];
        #pragma unroll
        for (int ks = 0; ks < 2; ++ks)
            xf[ks] = cvt8(X + (long)arow * 64 + ks * 32 + quad * 8);
        float4_t acc[4];
        #pragma unroll
        for (int ft = 0; ft < 4; ++ft) {
            acc[ft] = (float4_t){0.f, 0.f, 0.f, 0.f};
            #pragma unroll
            for (int ks = 0; ks < 2; ++ks)
                acc[ft] = __builtin_amdgcn_mfma_f32_16x16x32_f16(
                    xf[ks], wf[ft][ks], acc[ft], 0, 0, 0);
        }
        #pragma unroll
        for (int r = 0; r < 4; ++r) {
            const int row = rt * 16 + quad * 4 + r;     // (b*S+s)*H+h
            const int b = row >> 14;
            const int s = (row >> 3) & 2047;
            const int h = row & 7;
            const long orow = ((long)(b * NH + h) * S_LEN + s) * EMB;
            #pragma unroll
            for (int ft = 0; ft < 4; ++ft) {
                const _Float16 v =
                    (_Float16)(acc[ft][r] + bv[ft]) * (_Float16)0.125f;
                Out[orow + ft * 16 + l15] = (float)v;
            }
        }
    }
}

// ---------------------------------------------------------------------------
// Launch 2: K and V projections fused, writing attention-ready layouts:
//   seg 0: K -> KT8[bh][f/8][s][f%8]
//   seg 1: V -> VT8[bh][s/8][f][s%8]
// ---------------------------------------------------------------------------
__global__ __launch_bounds__(256) void proj_kv(
    const float* __restrict__ k_in, const float* __restrict__ v_in,
    const float* __restrict__ Wk, const float* __restrict__ bk,
    const float* __restrict__ Wv, const float* __restrict__ bv_,
    _Float16* __restrict__ KT8, _Float16* __restrict__ VT8)
{
    const int seg = blockIdx.x >> 8;          // 0=K, 1=V
    const int bid = blockIdx.x & 255;
    const float* X    = seg ? v_in : k_in;
    const float* W    = seg ? Wv : Wk;
    const float* bias = seg ? bv_ : bk;

    const int tid  = threadIdx.x;
    const int lane = tid & 63;
    const int wave = tid >> 6;
    const int l15  = lane & 15;
    const int quad = lane >> 4;
    const int gwave = bid * 4 + wave;

    half8 wf[4][2];
    #pragma unroll
    for (int ft = 0; ft < 4; ++ft)
        #pragma unroll
        for (int ks = 0; ks < 2; ++ks)
            wf[ft][ks] = cvt8(W + (ft * 16 + l15) * 64 + ks * 32 + quad * 8);
    float bv[4];
    #pragma unroll
    for (int ft = 0; ft < 4; ++ft) bv[ft] = bias[ft * 16 + l15];

    #pragma unroll
    for (int rt2 = 0; rt2 < 2; ++rt2) {
        const int rt = gwave * 2 + rt2;
        const int arow = rt * 16 + l15;
        half8 xf[2];
        #pragma unroll
        for (int ks = 0; ks < 2; ++ks)
            xf[ks] = cvt8(X + (long)arow * 64 + ks * 32 + quad * 8);
        float4_t acc[4];
        #pragma unroll
        for (int ft = 0; ft < 4; ++ft) {
            acc[ft] = (float4_t){0.f, 0.f, 0.f, 0.f};
            #pragma unroll
            for (int ks = 0; ks < 2; ++ks)
                acc[ft] = __builtin_amdgcn_mfma_f32_16x16x32_f16(
                    xf[ks], wf[ft][ks], acc[ft], 0, 0, 0);
        }
        #pragma unroll
        for (int r = 0; r < 4; ++r) {
            const int row = rt * 16 + quad * 4 + r;     // (b*S+s)*H+h
            const int b = row >> 14;
            const int s = (row >> 3) & 2047;
            const int h = row & 7;
            const int bh = b * NH + h;
            #pragma unroll
            for (int ft = 0; ft < 4; ++ft) {
                const _Float16 v = (_Float16)(acc[ft][r] + bv[ft]);
                const int f = ft * 16 + l15;
                if (seg == 0)
                    KT8[(((long)bh * 8 + (f >> 3)) * S_LEN + s) * 8 + (f & 7)] = v;
                else
                    VT8[(((long)bh * 256 + (s >> 3)) * 64 + f) * 8 + (s & 7)] = v;
            }
        }
    }
}

// ---------------------------------------------------------------------------
// Launch 3: flash attention partials, KV-split=3, S^T orientation, BN=64.
// LDS 25 KB/block -> 6 blocks/CU resident (grid = exactly 6x256). K/V tiles
// staged via global_load_lds and shared block-wide; S^T = K*Q^T so each lane
// owns one q-row -> scalar m/l, 2-shuffle reductions, b64 P stores.
// ---------------------------------------------------------------------------
__global__ __launch_bounds__(256, 6) void attn_part(
    const _Float16* __restrict__ KT, const _Float16* __restrict__ VT,
    const float* __restrict__ Qbuf,
    _Float16* __restrict__ p0, _Float16* __restrict__ p1,
    _Float16* __restrict__ p2, float* __restrict__ stats)
{
    __shared__ __align__(16) _Float16 Kb[8 * 64 * 8];    // 8 KB [ec][tl][ej]
    __shared__ __align__(16) _Float16 Vb[8 * 64 * 8];    // 8 KB [tc][e][tj]
    __shared__ __align__(16) _Float16 Pl[4][16 * PSTR];  // 9 KB per-wave P: [q][t]

    const int tid  = threadIdx.x;
    const int lane = tid & 63;
    const int wave = tid >> 6;
    const int l15  = lane & 15;
    const int quad = lane >> 4;
    const int bx   = blockIdx.x;
    const int bh   = bx / (32 * NSPLIT);
    const int rem  = bx % (32 * NSPLIT);
    const int qt   = rem / NSPLIT;
    const int sp   = rem % NSPLIT;
    const long base = (long)bh * S_LEN * EMB;
    const int qrow0 = qt * BM + wave * 16;

    const _Float16* kg = KT + (long)bh * 8 * S_LEN * 8;  // head base in KT8

    half8 qf[2];   // B-frag: Q[n = q-row l15][e = ks*32+quad*8+j]
    #pragma unroll
    for (int ks = 0; ks < 2; ++ks)
        qf[ks] = cvt8(Qbuf + base + (long)(qrow0 + l15) * EMB + ks * 32 + quad * 8);

    float4_t o[4];
    #pragma unroll
    for (int et = 0; et < 4; ++et) o[et] = (float4_t){0.f, 0.f, 0.f, 0.f};
    float m_run = M_INIT, l_run = 0.f;    // this lane's q-row = l15

    const int kb = (sp * NKT) / NSPLIT, ke = ((sp + 1) * NKT) / NSPLIT; // 10/11/11
    for (int kt = kb; kt < ke; ++kt) {
        if (kt > kb) __syncthreads();     // prev-iter consumers done
        const int t0 = kt * BN;
        #pragma unroll
        for (int rr = 0; rr < 2; ++rr) {  // K tile: 512 units [ec][tl][ej]
            const int u = rr * 256 + tid;
            const int ec = u >> 6, tl = u & 63;
            gload_lds16(kg + ((long)ec * S_LEN + t0 + tl) * 8, Kb + u * 8);
        }
        const _Float16* vg = VT + ((long)bh * 256 + (t0 >> 3)) * 512;
        #pragma unroll
        for (int rr = 0; rr < 2; ++rr) {  // V tile: contiguous 8 KB
            const int u = rr * 256 + tid;
            gload_lds16(vg + u * 8, Vb + u * 8);
        }
        __syncthreads();                  // drains vmcnt -> tiles visible

        // S^T = K Q^T : 4 n-tiles of 16 t-rows
        float4_t sacc[4];
        #pragma unroll
        for (int nt = 0; nt < 4; ++nt) sacc[nt] = (float4_t){0.f, 0.f, 0.f, 0.f};
        #pragma unroll
        for (int nt = 0; nt < 4; ++nt)
            #pragma unroll
            for (int ks = 0; ks < 2; ++ks) {
                half8 kf = *reinterpret_cast<const half8*>(   // A: K[m=t][e]
                    Kb + (ks * 4 + quad) * 512 + (nt * 16 + l15) * 8);
                sacc[nt] = __builtin_amdgcn_mfma_f32_16x16x32_f16(
                    kf, qf[ks], sacc[nt], 0, 0, 0);
            }

        // softmax for q-row l15: 16 local values (t = nt*16 + quad*4 + r)
        float mx = sacc[0][0];
        #pragma unroll
        for (int nt = 0; nt < 4; ++nt)
            #pragma unroll
            for (int r = 0; r < 4; ++r) mx = fmaxf(mx, sacc[nt][r]);
        mx = fmaxf(mx, __shfl_xor(mx, 16));
        mx = fmaxf(mx, __shfl_xor(mx, 32));

        const float mn = fmaxf(m_run, mx);
        const float alpha = __expf(fmaxf(m_run - mn, EXP_CLAMP));
        m_run = mn;

        _Float16* Pw = Pl[wave];
        float rsum = 0.f;
        #pragma unroll
        for (int nt = 0; nt < 4; ++nt) {
            half4 ph;
            #pragma unroll
            for (int r = 0; r < 4; ++r) {
                const float p = __expf(sacc[nt][r] - m_run);
                rsum += p;
                ph[r] = (_Float16)p;
            }
            // P[q=l15][t = nt*16 + quad*4 + 0..3] : one b64 write
            *reinterpret_cast<half4*>(&Pw[l15 * PSTR + nt * 16 + quad * 4]) = ph;
        }
        rsum += __shfl_xor(rsum, 16);
        rsum += __shfl_xor(rsum, 32);
        l_run = l_run * alpha + rsum;

        // rescale O (rows quad*4+r need alpha of lane quad*4+r)
        #pragma unroll
        for (int r = 0; r < 4; ++r) {
            const float ar = __shfl(alpha, quad * 4 + r);
            #pragma unroll
            for (int et = 0; et < 4; ++et) o[et][r] *= ar;
        }
        // no barrier: P write->read is intra-wave (compiler lgkmcnt)

        // O += P V : A-frag = P[m=l15][t=ts*32+quad*8+j], B-frag from Vb LDS
        #pragma unroll
        for (int ts = 0; ts < 2; ++ts) {
            half8 pf = *reinterpret_cast<const half8*>(
                &Pw[l15 * PSTR + ts * 32 + quad * 8]);
            #pragma unroll
            for (int et = 0; et < 4; ++et) {
                half8 vf = *reinterpret_cast<const half8*>(
                    Vb + (ts * 4 + quad) * 512 + (et * 16 + l15) * 8);
                o[et] = __builtin_amdgcn_mfma_f32_16x16x32_f16(pf, vf, o[et], 0, 0, 0);
            }
        }
    }

    // epilogue: normalized partial O-hat (f16) + (m,l) stats.
    _Float16* pp = (sp == 0) ? p0 : (sp == 1) ? p1 : p2;
    #pragma unroll
    for (int r = 0; r < 4; ++r) {
        const float lr = __shfl(l_run, quad * 4 + r);    // row quad*4+r's sum
        const float inv = 1.f / lr;
        const int row = qrow0 + quad * 4 + r;            // 0..2047 within head
        const int R = bh * S_LEN + row;                  // 0..32767 global row
        #pragma unroll
        for (int et = 0; et < 4; ++et)
            pp[(long)R * EMB + et * 16 + l15] = (_Float16)(o[et][r] * inv);
    }
    if (lane < 16) {                                     // lane i owns q-row i
        const int R = bh * S_LEN + qrow0 + lane;
        stats[sp * 32768 + R] = m_run;
        stats[(NSPLIT + sp) * 32768 + R] = l_run;
    }
}

// ---------------------------------------------------------------------------
// Launch 4: combine the 3 partials. O = sum w_i*Ohat_i, f16-round, f32 store.
// ---------------------------------------------------------------------------
__global__ __launch_bounds__(256) void attn_combine(
    const _Float16* __restrict__ p0, const _Float16* __restrict__ p1,
    const _Float16* __restrict__ p2, const float* __restrict__ stats,
    float* __restrict__ out)
{
    const int gid = blockIdx.x * 256 + threadIdx.x;      // 131072 threads
    const int R  = gid >> 2;
    const int c0 = (gid & 3) * 16;
    const float m0 = stats[R], m1 = stats[32768 + R], m2 = stats[2 * 32768 + R];
    const float l0 = stats[3 * 32768 + R], l1 = stats[4 * 32768 + R],
                l2 = stats[5 * 32768 + R];
    const float M = fmaxf(fmaxf(m0, m1), m2);
    float w0 = l0 * __expf(fmaxf(m0 - M, EXP_CLAMP));
    float w1 = l1 * __expf(fmaxf(m1 - M, EXP_CLAMP));
    float w2 = l2 * __expf(fmaxf(m2 - M, EXP_CLAMP));
    const float rinv = 1.f / (w0 + w1 + w2);
    w0 *= rinv; w1 *= rinv; w2 *= rinv;
    const long i0 = (long)R * EMB + c0;
    #pragma unroll
    for (int h = 0; h < 2; ++h) {
        half8 a = *reinterpret_cast<const half8*>(p0 + i0 + h * 8);
        half8 b = *reinterpret_cast<const half8*>(p1 + i0 + h * 8);
        half8 c = *reinterpret_cast<const half8*>(p2 + i0 + h * 8);
        #pragma unroll
        for (int j = 0; j < 8; ++j)
            out[i0 + h * 8 + j] = (float)(_Float16)(
                w0 * (float)a[j] + w1 * (float)b[j] + w2 * (float)c[j]);
    }
}

// ---------------------------------------------------------------------------
// 4 launches. Buffer plan (no d_ws; stream-ordered liveness):
//   L1 proj_q:  d_in[0](f32) -> d_out (f32, f16-rounded, pre-scaled)
//   L2 proj_kv: d_in[1] -> KT8 = d_in[0][0,4MB); d_in[2] -> VT8 = d_in[0][4,8MB)
//   L3 attn_part: reads KT8/VT8/d_out; p0,p1 -> d_in[2][0,8MB) (v_in dead),
//               p2 -> d_in[1][0,4MB) (k_in dead), stats -> d_in[1][4,4.75MB)
//   L4 combine -> d_out (Q dead)
// ---------------------------------------------------------------------------
extern "C" void kernel_launch(void* const* d_in, const int* in_sizes, int n_in,
                              void* d_out, int out_size, void* d_ws, size_t ws_size,
                              hipStream_t stream) {
    const float* q_in = (const float*)d_in[0];
    const float* k_in = (const float*)d_in[1];
    const float* v_in = (const float*)d_in[2];
    const float* Wq   = (const float*)d_in[3];
    const float* bq   = (const float*)d_in[4];
    const float* Wk   = (const float*)d_in[5];
    const float* bk   = (const float*)d_in[6];
    const float* Wv   = (const float*)d_in[7];
    const float* bv   = (const float*)d_in[8];
    float* out = (float*)d_out;

    _Float16* KT8   = (_Float16*)d_in[0];
    _Float16* VT8   = (_Float16*)((char*)d_in[0] + (4u << 20));
    _Float16* part0 = (_Float16*)d_in[2];
    _Float16* part1 = part0 + (long)2 * 1024 * 1024;           // +4 MB
    _Float16* part2 = (_Float16*)d_in[1];
    float*    stats = (float*)((char*)d_in[1] + (4u << 20));

    proj_q<<<256, 256, 0, stream>>>(q_in, Wq, bq, out);
    proj_kv<<<512, 256, 0, stream>>>(k_in, v_in, Wk, bk, Wv, bv, KT8, VT8);
    attn_part<<<16 * 32 * NSPLIT, 256, 0, stream>>>(KT8, VT8, out,
                                                    part0, part1, part2, stats);
    attn_combine<<<512, 256, 0, stream>>>(part0, part1, part2, stats, out);
}